// Round 10
// baseline (442.351 us; speedup 1.0000x reference)
//
#include <hip/hip_runtime.h>

// Problem: x [32,3,512,512] fp32, 30 Perona-Malik iterations, expand to 3ch.
#define BATCH 32
#define HGT 512
#define WID 512
#define PLANE (HGT * WID)            // 262144
#define NPIX (BATCH * PLANE)         // 8388608
#define BSTRIDE (3 * PLANE)          // batch stride in x and d_out
#define NQUAD (NPIX / 4)

// Fused-slab geometry: 512-thread block (8 waves) owns a 32-row slab with S
// halo rows each side. Static LDS (32+2S)*512*4B (80 KB @ S=4) -> 2 blocks/CU,
// 512 blocks = zero tail. One wave = one row-strip; lane owns cols 8o..8o+7.
//
// LDS rows are SWIZZLED at quad granularity: quad q lives at float offset
// (q&1)*256 + (q>>1)*4. A lane's two b128 reads (quads 2o and 2o+1) are then
// at 16B lane stride -> bank-conflict-free. The global u ping-pong buffers
// use the SAME swizzled layout, so staging is an identity copy and final-step
// u writes are fully coalesced.
#define RSLAB 32
#define SLABS (HGT / RSLAB)          // 16
#define FBLOCKS (BATCH * SLABS)      // 512
#define FT 512

__device__ __forceinline__ float4 ld4(const float* p) {
    return *reinterpret_cast<const float4*>(p);
}
__device__ __forceinline__ void st4(float* p, float4 v) {
    *reinterpret_cast<float4*>(p) = v;
}

// phi(d) = d / (1 + d^2/k^2); g even -> undirected edge flux shared with
// opposite signs by its two endpoint pixels.
__device__ __forceinline__ float pm_flux(float d, float ik2) {
    return d * __builtin_amdgcn_rcpf(fmaf(d * d, ik2, 1.f));
}

// Swizzled float offset of quad q within a row.
__device__ __forceinline__ int swz(int q) {
    return ((q & 1) << 8) + ((q >> 1) << 2);
}

// Load a 10-wide window (cols 8o-1 .. 8o+8) from a swizzled LDS row.
// Two conflict-free b128 + 2 wave shuffles (one wave per strip, lockstep).
__device__ __forceinline__ void load_row10(const float* __restrict__ buf, int row, int o,
                                           float m[10]) {
    const float* p = buf + row * WID + (o << 2);
    float4 lo = ld4(p);          // quad 2o   = cols 8o..8o+3
    float4 hi = ld4(p + 256);    // quad 2o+1 = cols 8o+4..8o+7
    float le = __shfl_up(hi.w, 1);      // lane o-1's col 8o-1
    float re = __shfl_down(lo.x, 1);    // lane o+1's col 8o+8
    m[0] = (o == 0) ? 0.f : le;
    m[1] = lo.x; m[2] = lo.y; m[3] = lo.z; m[4] = lo.w;
    m[5] = hi.x; m[6] = hi.y; m[7] = hi.z; m[8] = hi.w;
    m[9] = (o == 63) ? 0.f : re;
}

// ---------------------------------------------------------------------------
// Fused-S kernel. MODE 0: src = x linear (lum on load), dst = swizzled u.
// MODE 1: swizzled u -> swizzled u. MODE 2: swizzled u -> d_out (linear,
// expanded to 3 planes).
// In-place LDS trapezoid with delay-1 interior writeback: row r's result is
// written to LDS only after row r+1's result is computed (r's old value is
// last read by output r+1). Strip-boundary rows are held in registers and
// written between the two barriers.
// Fluxes are recomputed per row from the a/m/d windows (no rolling flux
// state) to keep live registers < 64 and avoid scratch spill.
// ---------------------------------------------------------------------------
template <int MODE, int S>
__global__ __launch_bounds__(FT, 4)
void pm_fusedk(const float* __restrict__ src, int sstr,
               float* __restrict__ dst, int dstr,
               const float* __restrict__ pdelta, const float* __restrict__ pkappa,
               const float* __restrict__ Wexp, const float* __restrict__ bexp) {
    constexpr int LR = RSLAB + 2 * S;
    __shared__ float buf[LR * WID];

    const int img  = blockIdx.x >> 4;         // / SLABS
    const int slab = blockIdx.x & (SLABS - 1);
    const int H0   = slab * RSLAB;
    const int tid  = threadIdx.x;
    const int wave = tid >> 6;                // 0..7
    const int o    = tid & 63;

    const float delta = *pdelta;
    const float kappa = *pkappa;
    const float ik2 = __builtin_amdgcn_rcpf(kappa * kappa);

    // ---- stage LR rows into LDS (rows outside image -> 0) ----
    const float* sb = src + (size_t)img * sstr;
    for (int i = tid; i < LR * (WID / 4); i += FT) {
        int row = i >> 7;
        int q   = i & 127;
        int g = H0 - S + row;
        float4 v = make_float4(0.f, 0.f, 0.f, 0.f);
        if ((unsigned)g < (unsigned)HGT) {
            const float* p = sb + g * WID + (q << 2);
            if (MODE == 0) {
                float4 r = ld4(p), gg = ld4(p + PLANE), bb = ld4(p + 2 * PLANE);
                v.x = fmaf(0.299f, r.x, fmaf(0.587f, gg.x, 0.114f * bb.x));
                v.y = fmaf(0.299f, r.y, fmaf(0.587f, gg.y, 0.114f * bb.y));
                v.z = fmaf(0.299f, r.z, fmaf(0.587f, gg.z, 0.114f * bb.z));
                v.w = fmaf(0.299f, r.w, fmaf(0.587f, gg.w, 0.114f * bb.w));
            } else {
                v = ld4(p);  // u is already stored swizzled: identity copy
            }
        }
        int dsto = (MODE == 0) ? swz(q) : (q << 2);
        st4(buf + row * WID + dsto, v);
    }
    __syncthreads();

    float s0c = 0.f, s1c = 0.f, s2c = 0.f, b0c = 0.f, b1c = 0.f, b2c = 0.f;
    if (MODE == 2) {
        s0c = Wexp[0] + Wexp[1] + Wexp[2];
        s1c = Wexp[3] + Wexp[4] + Wexp[5];
        s2c = Wexp[6] + Wexp[7] + Wexp[8];
        b0c = bexp[0]; b1c = bexp[1]; b2c = bexp[2];
    }

    float* db = dst + (size_t)img * dstr;

    for (int s = 0; s < S; ++s) {
        const int tot = LR - 2 - 2 * s;
        const int bse = tot >> 3, rem = tot & 7;
        const int n   = bse + (wave < rem ? 1 : 0);        // wave-uniform, >= 4
        const int st0 = s + 1 + wave * bse + (wave < rem ? wave : rem);
        const bool fin = (s == S - 1);

        float a[10], m[10], d[10];
        load_row10(buf, st0 - 1, o, a);
        load_row10(buf, st0, o, m);

        float f8[8], l8[8], rp[8];     // strip-top hold, strip-bottom hold, delay-1

        for (int i = 0; i < n; ++i) {
            load_row10(buf, st0 + i + 1, o, d);

            float hF[9];
#pragma unroll
            for (int t = 0; t < 9; ++t) hF[t] = pm_flux(m[t + 1] - m[t], ik2);

            float o8[8];
#pragma unroll
            for (int j = 0; j < 8; ++j) {
                float c = m[j + 1];
                float ax = hF[j + 1] - hF[j];
                ax += pm_flux(a[j + 1] - c, ik2);     // N
                ax += pm_flux(d[j + 1] - c, ik2);     // S
                float dg = pm_flux(a[j] - c, ik2);    // NW
                dg += pm_flux(a[j + 2] - c, ik2);     // NE
                dg += pm_flux(d[j] - c, ik2);         // SW
                dg += pm_flux(d[j + 2] - c, ik2);     // SE
                o8[j] = fmaf(delta, fmaf(0.5f, dg, ax), c);
            }

            const int g = H0 - S + st0 + i;
            if ((unsigned)g >= (unsigned)HGT) {
#pragma unroll
                for (int j = 0; j < 8; ++j) o8[j] = 0.f;
            }

            if (fin) {
                if (MODE == 2) {
                    // linear d_out write, 3 planes
                    float* p = db + (size_t)g * WID + (o << 3);
                    st4(p, make_float4(fmaf(s0c, o8[0], b0c), fmaf(s0c, o8[1], b0c),
                                       fmaf(s0c, o8[2], b0c), fmaf(s0c, o8[3], b0c)));
                    st4(p + 4, make_float4(fmaf(s0c, o8[4], b0c), fmaf(s0c, o8[5], b0c),
                                           fmaf(s0c, o8[6], b0c), fmaf(s0c, o8[7], b0c)));
                    st4(p + PLANE,
                        make_float4(fmaf(s1c, o8[0], b1c), fmaf(s1c, o8[1], b1c),
                                    fmaf(s1c, o8[2], b1c), fmaf(s1c, o8[3], b1c)));
                    st4(p + PLANE + 4,
                        make_float4(fmaf(s1c, o8[4], b1c), fmaf(s1c, o8[5], b1c),
                                    fmaf(s1c, o8[6], b1c), fmaf(s1c, o8[7], b1c)));
                    st4(p + 2 * PLANE,
                        make_float4(fmaf(s2c, o8[0], b2c), fmaf(s2c, o8[1], b2c),
                                    fmaf(s2c, o8[2], b2c), fmaf(s2c, o8[3], b2c)));
                    st4(p + 2 * PLANE + 4,
                        make_float4(fmaf(s2c, o8[4], b2c), fmaf(s2c, o8[5], b2c),
                                    fmaf(s2c, o8[6], b2c), fmaf(s2c, o8[7], b2c)));
                } else {
                    // swizzled u write: both stores 16B lane stride -> coalesced
                    float* p = db + (size_t)g * WID + (o << 2);
                    st4(p, make_float4(o8[0], o8[1], o8[2], o8[3]));
                    st4(p + 256, make_float4(o8[4], o8[5], o8[6], o8[7]));
                }
            } else if (i == 0) {
#pragma unroll
                for (int j = 0; j < 8; ++j) f8[j] = o8[j];
            } else {
                if (i >= 2) {
                    // delay-1 interior writeback: row st0+i-1's old value was
                    // last read by this output -> safe to overwrite now.
                    float* p = buf + (st0 + i - 1) * WID + (o << 2);
                    st4(p, make_float4(rp[0], rp[1], rp[2], rp[3]));
                    st4(p + 256, make_float4(rp[4], rp[5], rp[6], rp[7]));
                }
                if (i == n - 1) {
#pragma unroll
                    for (int j = 0; j < 8; ++j) l8[j] = o8[j];
                } else {
#pragma unroll
                    for (int j = 0; j < 8; ++j) rp[j] = o8[j];
                }
            }

            // roll windows down one row
#pragma unroll
            for (int t = 0; t < 10; ++t) { a[t] = m[t]; m[t] = d[t]; }
        }

        if (!fin) {
            __syncthreads();               // all strips done reading old rows
            float* p = buf + st0 * WID + (o << 2);
            st4(p, make_float4(f8[0], f8[1], f8[2], f8[3]));
            st4(p + 256, make_float4(f8[4], f8[5], f8[6], f8[7]));
            p = buf + (st0 + n - 1) * WID + (o << 2);
            st4(p, make_float4(l8[0], l8[1], l8[2], l8[3]));
            st4(p + 256, make_float4(l8[4], l8[5], l8[6], l8[7]));
            __syncthreads();               // boundary rows visible
        }
    }
}

// ---------------------------------------------------------------------------
// Fallback expand: reads SWIZZLED u from usrc, writes 3 linear planes of out.
// ---------------------------------------------------------------------------
__global__ void expand_from(const float* __restrict__ usrc, int ustr,
                            float* __restrict__ out,
                            const float* __restrict__ Wexp,
                            const float* __restrict__ bexp) {
    int idx = blockIdx.x * blockDim.x + threadIdx.x;
    if (idx >= NQUAD) return;
    int b = idx / (PLANE / 4);
    int pq = idx - b * (PLANE / 4);      // linear output quad within plane
    int row = pq >> 7;
    int q   = pq & 127;

    float4 u = ld4(usrc + (size_t)b * ustr + row * WID + swz(q));
    float s0 = Wexp[0] + Wexp[1] + Wexp[2];
    float s1 = Wexp[3] + Wexp[4] + Wexp[5];
    float s2 = Wexp[6] + Wexp[7] + Wexp[8];
    float b0 = bexp[0], b1 = bexp[1], b2 = bexp[2];

    size_t base = (size_t)b * BSTRIDE + row * WID + (q << 2);
    st4(out + base, make_float4(fmaf(s0, u.x, b0), fmaf(s0, u.y, b0),
                                fmaf(s0, u.z, b0), fmaf(s0, u.w, b0)));
    st4(out + base + PLANE, make_float4(fmaf(s1, u.x, b1), fmaf(s1, u.y, b1),
                                        fmaf(s1, u.z, b1), fmaf(s1, u.w, b1)));
    st4(out + base + 2 * PLANE, make_float4(fmaf(s2, u.x, b2), fmaf(s2, u.y, b2),
                                            fmaf(s2, u.z, b2), fmaf(s2, u.w, b2)));
}

extern "C" void kernel_launch(void* const* d_in, const int* in_sizes, int n_in,
                              void* d_out, int out_size, void* d_ws, size_t ws_size,
                              hipStream_t stream) {
    const float* x      = (const float*)d_in[0];
    const float* pdelta = (const float*)d_in[1];
    const float* pkappa = (const float*)d_in[2];
    const float* Wexp   = (const float*)d_in[3];
    const float* bexp   = (const float*)d_in[4];
    float* out = (float*)d_out;

    const size_t need = (size_t)2 * NPIX * sizeof(float);   // 64 MB
    if (ws_size >= need) {
        // 8 dispatches: [lum+steps1-4], 6x[4 steps] (5-28), [steps29-30+expand].
        float* uA = (float*)d_ws;
        float* uB = uA + NPIX;
        pm_fusedk<0, 4><<<FBLOCKS, FT, 0, stream>>>(
            x, BSTRIDE, uA, PLANE, pdelta, pkappa, Wexp, bexp);
        float* s = uA;
        float* d = uB;
        for (int k = 0; k < 6; ++k) {
            pm_fusedk<1, 4><<<FBLOCKS, FT, 0, stream>>>(
                s, PLANE, d, PLANE, pdelta, pkappa, Wexp, bexp);
            float* t = s; s = d; d = t;
        }
        // u28 is in s. Final 2 steps + expand; d_out written exactly once.
        pm_fusedk<2, 2><<<FBLOCKS, FT, 0, stream>>>(
            s, PLANE, out, BSTRIDE, pdelta, pkappa, Wexp, bexp);
    } else {
        // Fallback: ping-pong in d_out planes 0/1 (swizzled), separate expand.
        float* uA = out;            // plane 0
        float* uB = out + PLANE;    // plane 1
        pm_fusedk<0, 4><<<FBLOCKS, FT, 0, stream>>>(
            x, BSTRIDE, uA, BSTRIDE, pdelta, pkappa, Wexp, bexp);
        float* s = uA;
        float* d = uB;
        for (int k = 0; k < 6; ++k) {
            pm_fusedk<1, 4><<<FBLOCKS, FT, 0, stream>>>(
                s, BSTRIDE, d, BSTRIDE, pdelta, pkappa, Wexp, bexp);
            float* t = s; s = d; d = t;
        }
        // u28 in s; 2 more steps into d, then expand from d (swizzled).
        pm_fusedk<1, 2><<<FBLOCKS, FT, 0, stream>>>(
            s, BSTRIDE, d, BSTRIDE, pdelta, pkappa, Wexp, bexp);
        const int block = 256;
        const int grid_q = (NQUAD + block - 1) / block;
        expand_from<<<grid_q, block, 0, stream>>>(d, BSTRIDE, out, Wexp, bexp);
    }
}

// Round 11
// 404.714 us; speedup vs baseline: 1.0930x; 1.0930x over previous
//
#include <hip/hip_runtime.h>

// Problem: x [32,3,512,512] fp32, 30 Perona-Malik iterations, expand to 3ch.
#define BATCH 32
#define HGT 512
#define WID 512
#define PLANE (HGT * WID)            // 262144
#define NPIX (BATCH * PLANE)         // 8388608
#define BSTRIDE (3 * PLANE)          // batch stride in x and d_out
#define NQUAD (NPIX / 4)

// Fused-slab geometry: 512-thread block (8 waves) owns a 32-row slab with S
// halo rows each side. Static LDS (32+2S)*512*4B (80 KB @ S=4) -> 2 blocks/CU,
// 512 blocks = zero tail. One wave = one row-strip; lane owns cols 8o..8o+7.
//
// LDS rows are SWIZZLED at quad granularity: quad q at float offset
// (q&1)*256 + (q>>1)*4, so a lane's two b128 reads (quads 2o, 2o+1) are at
// 16B lane stride -> bank-conflict-free (verified: conflicts dropped by the
// b128 share in round 10). Global u ping-pong buffers use the same swizzled
// layout (staging = identity copy; u writes coalesced).
#define RSLAB 32
#define SLABS (HGT / RSLAB)          // 16
#define FBLOCKS (BATCH * SLABS)      // 512
#define FT 512

__device__ __forceinline__ float4 ld4(const float* p) {
    return *reinterpret_cast<const float4*>(p);
}
__device__ __forceinline__ void st4(float* p, float4 v) {
    *reinterpret_cast<float4*>(p) = v;
}

// phi(d) = k^2*d/(k^2+d^2)  (== d/(1+d^2/k^2)).  3 VALU + 1 trans:
// fma(d,d,k2), mul(k2,d), mul.  g even -> undirected edge flux shared with
// opposite signs by both endpoint pixels.
__device__ __forceinline__ float pm_flux(float d, float k2) {
    return (k2 * d) * __builtin_amdgcn_rcpf(fmaf(d, d, k2));
}

// Swizzled float offset of quad q within a row.
__device__ __forceinline__ int swz(int q) {
    return ((q & 1) << 8) + ((q >> 1) << 2);
}

// Load a 10-wide window (cols 8o-1 .. 8o+8) from a swizzled LDS row.
// Two conflict-free b128 + 2 wave shuffles (one wave per strip, lockstep).
__device__ __forceinline__ void load_row10(const float* __restrict__ buf, int row, int o,
                                           float m[10]) {
    const float* p = buf + row * WID + (o << 2);
    float4 lo = ld4(p);          // quad 2o   = cols 8o..8o+3
    float4 hi = ld4(p + 256);    // quad 2o+1 = cols 8o+4..8o+7
    float le = __shfl_up(hi.w, 1);      // lane o-1's col 8o-1
    float re = __shfl_down(lo.x, 1);    // lane o+1's col 8o+8
    m[0] = (o == 0) ? 0.f : le;
    m[1] = lo.x; m[2] = lo.y; m[3] = lo.z; m[4] = lo.w;
    m[5] = hi.x; m[6] = hi.y; m[7] = hi.z; m[8] = hi.w;
    m[9] = (o == 63) ? 0.f : re;
}

// Rolling state: row data window m + fluxes to the row ABOVE (pV/pSE/pSW).
struct FluxState {
    float m[10];
    float pV[8], pSE[9], pSW[9];
};

// Level fluxes between row a (upper window) and row b (lower window).
__device__ __forceinline__ void level10(const float a[10], const float b[10],
                                        float vF[8], float seF[9], float swF[9],
                                        float k2) {
#pragma unroll
    for (int j = 0; j < 8; ++j) vF[j] = pm_flux(b[j + 1] - a[j + 1], k2);
#pragma unroll
    for (int i = 0; i < 9; ++i) seF[i] = pm_flux(b[i + 1] - a[i], k2);
#pragma unroll
    for (int i = 0; i < 9; ++i) swF[i] = pm_flux(b[i] - a[i + 1], k2);
}

// ---------------------------------------------------------------------------
// Fused-S kernel. MODE 0: src = x linear (lum on load), dst = swizzled u.
// MODE 1: swizzled u -> swizzled u. MODE 2: swizzled u -> d_out (linear, 3
// planes). In-place LDS trapezoid: interior rows written back immediately
// (wave-private, lockstep-safe), strip-boundary rows held in registers and
// written between the two barriers. Rolling flux state, zero-copy via static
// CUR/NXT ping-pong (round-8 style).
// ---------------------------------------------------------------------------
template <int MODE, int S>
__global__ __launch_bounds__(FT, 4)
void pm_fusedk(const float* __restrict__ src, int sstr,
               float* __restrict__ dst, int dstr,
               const float* __restrict__ pdelta, const float* __restrict__ pkappa,
               const float* __restrict__ Wexp, const float* __restrict__ bexp) {
    constexpr int LR = RSLAB + 2 * S;
    __shared__ float buf[LR * WID];

    const int img  = blockIdx.x >> 4;         // / SLABS
    const int slab = blockIdx.x & (SLABS - 1);
    const int H0   = slab * RSLAB;
    const int tid  = threadIdx.x;
    const int wave = tid >> 6;                // 0..7
    const int o    = tid & 63;

    const float delta = *pdelta;
    const float kappa = *pkappa;
    const float k2 = kappa * kappa;

    // ---- stage LR rows into LDS (rows outside image -> 0) ----
    const float* sb = src + (size_t)img * sstr;
    for (int i = tid; i < LR * (WID / 4); i += FT) {
        int row = i >> 7;
        int q   = i & 127;
        int g = H0 - S + row;
        float4 v = make_float4(0.f, 0.f, 0.f, 0.f);
        if ((unsigned)g < (unsigned)HGT) {
            const float* p = sb + g * WID + (q << 2);
            if (MODE == 0) {
                float4 r = ld4(p), gg = ld4(p + PLANE), bb = ld4(p + 2 * PLANE);
                v.x = fmaf(0.299f, r.x, fmaf(0.587f, gg.x, 0.114f * bb.x));
                v.y = fmaf(0.299f, r.y, fmaf(0.587f, gg.y, 0.114f * bb.y));
                v.z = fmaf(0.299f, r.z, fmaf(0.587f, gg.z, 0.114f * bb.z));
                v.w = fmaf(0.299f, r.w, fmaf(0.587f, gg.w, 0.114f * bb.w));
            } else {
                v = ld4(p);  // u already stored swizzled: identity copy
            }
        }
        int dsto = (MODE == 0) ? swz(q) : (q << 2);
        st4(buf + row * WID + dsto, v);
    }
    __syncthreads();

    float s0c = 0.f, s1c = 0.f, s2c = 0.f, b0c = 0.f, b1c = 0.f, b2c = 0.f;
    if (MODE == 2) {
        s0c = Wexp[0] + Wexp[1] + Wexp[2];
        s1c = Wexp[3] + Wexp[4] + Wexp[5];
        s2c = Wexp[6] + Wexp[7] + Wexp[8];
        b0c = bexp[0]; b1c = bexp[1]; b2c = bexp[2];
    }

    float* db = dst + (size_t)img * dstr;

    for (int s = 0; s < S; ++s) {
        const int tot = LR - 2 - 2 * s;
        const int bse = tot >> 3, rem = tot & 7;
        const int n   = bse + (wave < rem ? 1 : 0);        // wave-uniform, 4..5
        const int st0 = s + 1 + wave * bse + (wave < rem ? wave : rem);
        const bool fin = (s == S - 1);

        FluxState A, B;
        {
            float a10[10];
            load_row10(buf, st0 - 1, o, a10);
            load_row10(buf, st0, o, A.m);
            level10(a10, A.m, A.pV, A.pSE, A.pSW, k2);
        }
        float f8[8], l8[8];

        // One row: load next row + its level-fluxes into NXT (zero-copy roll),
        // emit output for CUR's row.
        auto do_row = [&](FluxState& CUR, FluxState& NXT, int i) {
            load_row10(buf, st0 + i + 1, o, NXT.m);
            float hF[9];
#pragma unroll
            for (int t = 0; t < 9; ++t) hF[t] = pm_flux(CUR.m[t + 1] - CUR.m[t], k2);
            level10(CUR.m, NXT.m, NXT.pV, NXT.pSE, NXT.pSW, k2);
            float o8[8];
#pragma unroll
            for (int j = 0; j < 8; ++j) {
                float ax = NXT.pV[j] - CUR.pV[j] + hF[j + 1] - hF[j];
                float dg = NXT.pSE[j + 1] + NXT.pSW[j]
                         - CUR.pSE[j] - CUR.pSW[j + 1];
                o8[j] = fmaf(delta, fmaf(0.5f, dg, ax), CUR.m[j + 1]);
            }
            const int g = H0 - S + st0 + i;
            if ((unsigned)g >= (unsigned)HGT) {
#pragma unroll
                for (int j = 0; j < 8; ++j) o8[j] = 0.f;
            }
            if (fin) {
                if (MODE == 2) {
                    float* p = db + (size_t)g * WID + (o << 3);
                    st4(p, make_float4(fmaf(s0c, o8[0], b0c), fmaf(s0c, o8[1], b0c),
                                       fmaf(s0c, o8[2], b0c), fmaf(s0c, o8[3], b0c)));
                    st4(p + 4, make_float4(fmaf(s0c, o8[4], b0c), fmaf(s0c, o8[5], b0c),
                                           fmaf(s0c, o8[6], b0c), fmaf(s0c, o8[7], b0c)));
                    st4(p + PLANE,
                        make_float4(fmaf(s1c, o8[0], b1c), fmaf(s1c, o8[1], b1c),
                                    fmaf(s1c, o8[2], b1c), fmaf(s1c, o8[3], b1c)));
                    st4(p + PLANE + 4,
                        make_float4(fmaf(s1c, o8[4], b1c), fmaf(s1c, o8[5], b1c),
                                    fmaf(s1c, o8[6], b1c), fmaf(s1c, o8[7], b1c)));
                    st4(p + 2 * PLANE,
                        make_float4(fmaf(s2c, o8[0], b2c), fmaf(s2c, o8[1], b2c),
                                    fmaf(s2c, o8[2], b2c), fmaf(s2c, o8[3], b2c)));
                    st4(p + 2 * PLANE + 4,
                        make_float4(fmaf(s2c, o8[4], b2c), fmaf(s2c, o8[5], b2c),
                                    fmaf(s2c, o8[6], b2c), fmaf(s2c, o8[7], b2c)));
                } else {
                    // swizzled u write: 16B lane stride, coalesced 1KB spans
                    float* p = db + (size_t)g * WID + (o << 2);
                    st4(p, make_float4(o8[0], o8[1], o8[2], o8[3]));
                    st4(p + 256, make_float4(o8[4], o8[5], o8[6], o8[7]));
                }
            } else if (i == 0) {
#pragma unroll
                for (int j = 0; j < 8; ++j) f8[j] = o8[j];      // strip-top hold
            } else if (i == n - 1) {
#pragma unroll
                for (int j = 0; j < 8; ++j) l8[j] = o8[j];      // strip-bottom hold
            } else {
                // interior row: wave-private, its old data lives in CUR.m regs
                float* p = buf + (st0 + i) * WID + (o << 2);
                st4(p, make_float4(o8[0], o8[1], o8[2], o8[3]));
                st4(p + 256, make_float4(o8[4], o8[5], o8[6], o8[7]));
            }
        };

        for (int i = 0; i < n; i += 2) {
            do_row(A, B, i);
            if (i + 1 < n) do_row(B, A, i + 1);
        }

        if (!fin) {
            __syncthreads();               // all strips done reading old rows
            float* p = buf + st0 * WID + (o << 2);
            st4(p, make_float4(f8[0], f8[1], f8[2], f8[3]));
            st4(p + 256, make_float4(f8[4], f8[5], f8[6], f8[7]));
            p = buf + (st0 + n - 1) * WID + (o << 2);
            st4(p, make_float4(l8[0], l8[1], l8[2], l8[3]));
            st4(p + 256, make_float4(l8[4], l8[5], l8[6], l8[7]));
            __syncthreads();               // boundary rows visible
        }
    }
}

// ---------------------------------------------------------------------------
// Fallback expand: reads SWIZZLED u from usrc, writes 3 linear planes of out.
// ---------------------------------------------------------------------------
__global__ void expand_from(const float* __restrict__ usrc, int ustr,
                            float* __restrict__ out,
                            const float* __restrict__ Wexp,
                            const float* __restrict__ bexp) {
    int idx = blockIdx.x * blockDim.x + threadIdx.x;
    if (idx >= NQUAD) return;
    int b = idx / (PLANE / 4);
    int pq = idx - b * (PLANE / 4);      // linear output quad within plane
    int row = pq >> 7;
    int q   = pq & 127;

    float4 u = ld4(usrc + (size_t)b * ustr + row * WID + swz(q));
    float s0 = Wexp[0] + Wexp[1] + Wexp[2];
    float s1 = Wexp[3] + Wexp[4] + Wexp[5];
    float s2 = Wexp[6] + Wexp[7] + Wexp[8];
    float b0 = bexp[0], b1 = bexp[1], b2 = bexp[2];

    size_t base = (size_t)b * BSTRIDE + row * WID + (q << 2);
    st4(out + base, make_float4(fmaf(s0, u.x, b0), fmaf(s0, u.y, b0),
                                fmaf(s0, u.z, b0), fmaf(s0, u.w, b0)));
    st4(out + base + PLANE, make_float4(fmaf(s1, u.x, b1), fmaf(s1, u.y, b1),
                                        fmaf(s1, u.z, b1), fmaf(s1, u.w, b1)));
    st4(out + base + 2 * PLANE, make_float4(fmaf(s2, u.x, b2), fmaf(s2, u.y, b2),
                                            fmaf(s2, u.z, b2), fmaf(s2, u.w, b2)));
}

extern "C" void kernel_launch(void* const* d_in, const int* in_sizes, int n_in,
                              void* d_out, int out_size, void* d_ws, size_t ws_size,
                              hipStream_t stream) {
    const float* x      = (const float*)d_in[0];
    const float* pdelta = (const float*)d_in[1];
    const float* pkappa = (const float*)d_in[2];
    const float* Wexp   = (const float*)d_in[3];
    const float* bexp   = (const float*)d_in[4];
    float* out = (float*)d_out;

    const size_t need = (size_t)2 * NPIX * sizeof(float);   // 64 MB
    if (ws_size >= need) {
        // 8 dispatches: [lum+steps1-4], 6x[4 steps] (5-28), [steps29-30+expand].
        float* uA = (float*)d_ws;
        float* uB = uA + NPIX;
        pm_fusedk<0, 4><<<FBLOCKS, FT, 0, stream>>>(
            x, BSTRIDE, uA, PLANE, pdelta, pkappa, Wexp, bexp);
        float* s = uA;
        float* d = uB;
        for (int k = 0; k < 6; ++k) {
            pm_fusedk<1, 4><<<FBLOCKS, FT, 0, stream>>>(
                s, PLANE, d, PLANE, pdelta, pkappa, Wexp, bexp);
            float* t = s; s = d; d = t;
        }
        // u28 is in s. Final 2 steps + expand; d_out written exactly once.
        pm_fusedk<2, 2><<<FBLOCKS, FT, 0, stream>>>(
            s, PLANE, out, BSTRIDE, pdelta, pkappa, Wexp, bexp);
    } else {
        // Fallback: ping-pong in d_out planes 0/1 (swizzled), separate expand.
        float* uA = out;            // plane 0
        float* uB = out + PLANE;    // plane 1
        pm_fusedk<0, 4><<<FBLOCKS, FT, 0, stream>>>(
            x, BSTRIDE, uA, BSTRIDE, pdelta, pkappa, Wexp, bexp);
        float* s = uA;
        float* d = uB;
        for (int k = 0; k < 6; ++k) {
            pm_fusedk<1, 4><<<FBLOCKS, FT, 0, stream>>>(
                s, BSTRIDE, d, BSTRIDE, pdelta, pkappa, Wexp, bexp);
            float* t = s; s = d; d = t;
        }
        // u28 in s; 2 more steps into d, then expand from d (swizzled).
        pm_fusedk<1, 2><<<FBLOCKS, FT, 0, stream>>>(
            s, BSTRIDE, d, BSTRIDE, pdelta, pkappa, Wexp, bexp);
        const int block = 256;
        const int grid_q = (NQUAD + block - 1) / block;
        expand_from<<<grid_q, block, 0, stream>>>(d, BSTRIDE, out, Wexp, bexp);
    }
}

// Round 12
// 403.490 us; speedup vs baseline: 1.0963x; 1.0030x over previous
//
#include <hip/hip_runtime.h>

// Problem: x [32,3,512,512] fp32, 30 Perona-Malik iterations, expand to 3ch.
#define BATCH 32
#define HGT 512
#define WID 512
#define PLANE (HGT * WID)            // 262144
#define NPIX (BATCH * PLANE)         // 8388608
#define BSTRIDE (3 * PLANE)          // batch stride in x and d_out
#define NQUAD (NPIX / 4)

// Round-6 winning skeleton: 1024-thread block (16 waves) owns a 64-row slab
// (+S halo rows each side). 256 blocks = exactly 1/CU, zero tail. One wave =
// one row-strip; lane owns cols 8o..8o+7.
// Grafts: (a) swizzled LDS rows -> conflict-free b128 (verified r10/r11),
// (b) 3-op flux form. Static LDS (144KB @ S=4).
#define RSLAB 64
#define SLABS (HGT / RSLAB)          // 8
#define FBLOCKS (BATCH * SLABS)      // 256
#define FT 1024

__device__ __forceinline__ float4 ld4(const float* p) {
    return *reinterpret_cast<const float4*>(p);
}
__device__ __forceinline__ void st4(float* p, float4 v) {
    *reinterpret_cast<float4*>(p) = v;
}

// phi(d) = k^2*d/(k^2+d^2) (== d/(1+d^2/k^2)): fma + 2 mul + rcp.
// g even -> undirected edge flux shared with opposite signs.
__device__ __forceinline__ float pm_flux(float d, float k2) {
    return (k2 * d) * __builtin_amdgcn_rcpf(fmaf(d, d, k2));
}

// Swizzled float offset of quad q within a row: quad q lives at
// (q&1)*256 + (q>>1)*4. Lane o's two quads (2o, 2o+1) are then at 16B lane
// stride at bases (o<<2) and (o<<2)+256 -> bank-conflict-free b128.
__device__ __forceinline__ int swz(int q) {
    return ((q & 1) << 8) + ((q >> 1) << 2);
}

// Load a 10-wide window (cols 8o-1 .. 8o+8) from a swizzled LDS row.
// 2 conflict-free b128 + 2 wave shuffles (one wave per strip, lockstep).
__device__ __forceinline__ void load_row10(const float* __restrict__ buf, int row, int o,
                                           float m[10]) {
    const float* p = buf + row * WID + (o << 2);
    float4 lo = ld4(p);          // quad 2o   = cols 8o..8o+3
    float4 hi = ld4(p + 256);    // quad 2o+1 = cols 8o+4..8o+7
    float le = __shfl_up(hi.w, 1);      // lane o-1's col 8o-1
    float re = __shfl_down(lo.x, 1);    // lane o+1's col 8o+8
    m[0] = (o == 0) ? 0.f : le;
    m[1] = lo.x; m[2] = lo.y; m[3] = lo.z; m[4] = lo.w;
    m[5] = hi.x; m[6] = hi.y; m[7] = hi.z; m[8] = hi.w;
    m[9] = (o == 63) ? 0.f : re;
}

// Rolling state: row window m + fluxes to the row ABOVE.
struct FluxState {
    float m[10];
    float pV[8], pSE[9], pSW[9];
};

__device__ __forceinline__ void level10(const float a[10], const float b[10],
                                        float vF[8], float seF[9], float swF[9],
                                        float k2) {
#pragma unroll
    for (int j = 0; j < 8; ++j) vF[j] = pm_flux(b[j + 1] - a[j + 1], k2);
#pragma unroll
    for (int i = 0; i < 9; ++i) seF[i] = pm_flux(b[i + 1] - a[i], k2);
#pragma unroll
    for (int i = 0; i < 9; ++i) swF[i] = pm_flux(b[i] - a[i + 1], k2);
}

// ---------------------------------------------------------------------------
// Fused-S kernel. MODE 0: src = x linear (lum on load), dst = swizzled u.
// MODE 1: swizzled u -> swizzled u. MODE 2: swizzled u -> d_out (linear,
// 3 planes). In-place LDS trapezoid: interior rows written back immediately
// (wave-private, lockstep-safe); strip-boundary rows held in regs and written
// between the two barriers. Rolling flux via static CUR/NXT ping-pong.
// ---------------------------------------------------------------------------
template <int MODE, int S>
__global__ __launch_bounds__(FT, 4)
void pm_fusedk(const float* __restrict__ src, int sstr,
               float* __restrict__ dst, int dstr,
               const float* __restrict__ pdelta, const float* __restrict__ pkappa,
               const float* __restrict__ Wexp, const float* __restrict__ bexp) {
    constexpr int LR = RSLAB + 2 * S;
    __shared__ float buf[LR * WID];           // 144 KB @ S=4 -> 1 block/CU

    const int img  = blockIdx.x >> 3;         // / SLABS
    const int slab = blockIdx.x & (SLABS - 1);
    const int H0   = slab * RSLAB;
    const int tid  = threadIdx.x;
    const int wave = tid >> 6;                // 0..15
    const int o    = tid & 63;

    const float delta = *pdelta;
    const float kappa = *pkappa;
    const float k2 = kappa * kappa;

    // ---- stage LR rows into LDS (rows outside image -> 0) ----
    const float* sb = src + (size_t)img * sstr;
    for (int i = tid; i < LR * (WID / 4); i += FT) {
        int row = i >> 7;
        int q   = i & 127;
        int g = H0 - S + row;
        float4 v = make_float4(0.f, 0.f, 0.f, 0.f);
        if ((unsigned)g < (unsigned)HGT) {
            const float* p = sb + g * WID + (q << 2);
            if (MODE == 0) {
                float4 r = ld4(p), gg = ld4(p + PLANE), bb = ld4(p + 2 * PLANE);
                v.x = fmaf(0.299f, r.x, fmaf(0.587f, gg.x, 0.114f * bb.x));
                v.y = fmaf(0.299f, r.y, fmaf(0.587f, gg.y, 0.114f * bb.y));
                v.z = fmaf(0.299f, r.z, fmaf(0.587f, gg.z, 0.114f * bb.z));
                v.w = fmaf(0.299f, r.w, fmaf(0.587f, gg.w, 0.114f * bb.w));
            } else {
                v = ld4(p);  // u already stored swizzled: identity copy
            }
        }
        int dsto = (MODE == 0) ? swz(q) : (q << 2);
        st4(buf + row * WID + dsto, v);
    }
    __syncthreads();

    float s0c = 0.f, s1c = 0.f, s2c = 0.f, b0c = 0.f, b1c = 0.f, b2c = 0.f;
    if (MODE == 2) {
        s0c = Wexp[0] + Wexp[1] + Wexp[2];
        s1c = Wexp[3] + Wexp[4] + Wexp[5];
        s2c = Wexp[6] + Wexp[7] + Wexp[8];
        b0c = bexp[0]; b1c = bexp[1]; b2c = bexp[2];
    }

    float* db = dst + (size_t)img * dstr;

    for (int s = 0; s < S; ++s) {
        const int tot = LR - 2 - 2 * s;
        const int bse = tot >> 4, rem = tot & 15;
        const int n   = bse + (wave < rem ? 1 : 0);        // wave-uniform, 4..5
        const int st0 = s + 1 + wave * bse + (wave < rem ? wave : rem);
        const bool fin = (s == S - 1);

        FluxState A, B;
        {
            float a10[10];
            load_row10(buf, st0 - 1, o, a10);
            load_row10(buf, st0, o, A.m);
            level10(a10, A.m, A.pV, A.pSE, A.pSW, k2);
        }
        float f8[8], l8[8];

        auto do_row = [&](FluxState& CUR, FluxState& NXT, int i) {
            load_row10(buf, st0 + i + 1, o, NXT.m);
            float hF[9];
#pragma unroll
            for (int t = 0; t < 9; ++t) hF[t] = pm_flux(CUR.m[t + 1] - CUR.m[t], k2);
            level10(CUR.m, NXT.m, NXT.pV, NXT.pSE, NXT.pSW, k2);
            float o8[8];
#pragma unroll
            for (int j = 0; j < 8; ++j) {
                float ax = NXT.pV[j] - CUR.pV[j] + hF[j + 1] - hF[j];
                float dg = NXT.pSE[j + 1] + NXT.pSW[j]
                         - CUR.pSE[j] - CUR.pSW[j + 1];
                o8[j] = fmaf(delta, fmaf(0.5f, dg, ax), CUR.m[j + 1]);
            }
            const int g = H0 - S + st0 + i;
            if ((unsigned)g >= (unsigned)HGT) {
#pragma unroll
                for (int j = 0; j < 8; ++j) o8[j] = 0.f;
            }
            if (fin) {
                if (MODE == 2) {
                    float* p = db + (size_t)g * WID + (o << 3);
                    st4(p, make_float4(fmaf(s0c, o8[0], b0c), fmaf(s0c, o8[1], b0c),
                                       fmaf(s0c, o8[2], b0c), fmaf(s0c, o8[3], b0c)));
                    st4(p + 4, make_float4(fmaf(s0c, o8[4], b0c), fmaf(s0c, o8[5], b0c),
                                           fmaf(s0c, o8[6], b0c), fmaf(s0c, o8[7], b0c)));
                    st4(p + PLANE,
                        make_float4(fmaf(s1c, o8[0], b1c), fmaf(s1c, o8[1], b1c),
                                    fmaf(s1c, o8[2], b1c), fmaf(s1c, o8[3], b1c)));
                    st4(p + PLANE + 4,
                        make_float4(fmaf(s1c, o8[4], b1c), fmaf(s1c, o8[5], b1c),
                                    fmaf(s1c, o8[6], b1c), fmaf(s1c, o8[7], b1c)));
                    st4(p + 2 * PLANE,
                        make_float4(fmaf(s2c, o8[0], b2c), fmaf(s2c, o8[1], b2c),
                                    fmaf(s2c, o8[2], b2c), fmaf(s2c, o8[3], b2c)));
                    st4(p + 2 * PLANE + 4,
                        make_float4(fmaf(s2c, o8[4], b2c), fmaf(s2c, o8[5], b2c),
                                    fmaf(s2c, o8[6], b2c), fmaf(s2c, o8[7], b2c)));
                } else {
                    // swizzled u write: both halves contiguous 1KB spans
                    float* p = db + (size_t)g * WID + (o << 2);
                    st4(p, make_float4(o8[0], o8[1], o8[2], o8[3]));
                    st4(p + 256, make_float4(o8[4], o8[5], o8[6], o8[7]));
                }
            } else if (i == 0) {
#pragma unroll
                for (int j = 0; j < 8; ++j) f8[j] = o8[j];      // strip-top hold
            } else if (i == n - 1) {
#pragma unroll
                for (int j = 0; j < 8; ++j) l8[j] = o8[j];      // strip-bottom hold
            } else {
                // interior row: wave-private, old data lives in CUR.m regs
                float* p = buf + (st0 + i) * WID + (o << 2);
                st4(p, make_float4(o8[0], o8[1], o8[2], o8[3]));
                st4(p + 256, make_float4(o8[4], o8[5], o8[6], o8[7]));
            }
        };

        for (int i = 0; i < n; i += 2) {
            do_row(A, B, i);
            if (i + 1 < n) do_row(B, A, i + 1);
        }

        if (!fin) {
            __syncthreads();               // all strips done reading old rows
            float* p = buf + st0 * WID + (o << 2);
            st4(p, make_float4(f8[0], f8[1], f8[2], f8[3]));
            st4(p + 256, make_float4(f8[4], f8[5], f8[6], f8[7]));
            p = buf + (st0 + n - 1) * WID + (o << 2);
            st4(p, make_float4(l8[0], l8[1], l8[2], l8[3]));
            st4(p + 256, make_float4(l8[4], l8[5], l8[6], l8[7]));
            __syncthreads();               // boundary rows visible
        }
    }
}

// ---------------------------------------------------------------------------
// Fallback expand: reads SWIZZLED u from usrc, writes 3 linear planes of out.
// ---------------------------------------------------------------------------
__global__ void expand_from(const float* __restrict__ usrc, int ustr,
                            float* __restrict__ out,
                            const float* __restrict__ Wexp,
                            const float* __restrict__ bexp) {
    int idx = blockIdx.x * blockDim.x + threadIdx.x;
    if (idx >= NQUAD) return;
    int b = idx / (PLANE / 4);
    int pq = idx - b * (PLANE / 4);
    int row = pq >> 7;
    int q   = pq & 127;

    float4 u = ld4(usrc + (size_t)b * ustr + row * WID + swz(q));
    float s0 = Wexp[0] + Wexp[1] + Wexp[2];
    float s1 = Wexp[3] + Wexp[4] + Wexp[5];
    float s2 = Wexp[6] + Wexp[7] + Wexp[8];
    float b0 = bexp[0], b1 = bexp[1], b2 = bexp[2];

    size_t base = (size_t)b * BSTRIDE + row * WID + (q << 2);
    st4(out + base, make_float4(fmaf(s0, u.x, b0), fmaf(s0, u.y, b0),
                                fmaf(s0, u.z, b0), fmaf(s0, u.w, b0)));
    st4(out + base + PLANE, make_float4(fmaf(s1, u.x, b1), fmaf(s1, u.y, b1),
                                        fmaf(s1, u.z, b1), fmaf(s1, u.w, b1)));
    st4(out + base + 2 * PLANE, make_float4(fmaf(s2, u.x, b2), fmaf(s2, u.y, b2),
                                            fmaf(s2, u.z, b2), fmaf(s2, u.w, b2)));
}

extern "C" void kernel_launch(void* const* d_in, const int* in_sizes, int n_in,
                              void* d_out, int out_size, void* d_ws, size_t ws_size,
                              hipStream_t stream) {
    const float* x      = (const float*)d_in[0];
    const float* pdelta = (const float*)d_in[1];
    const float* pkappa = (const float*)d_in[2];
    const float* Wexp   = (const float*)d_in[3];
    const float* bexp   = (const float*)d_in[4];
    float* out = (float*)d_out;

    const size_t need = (size_t)2 * NPIX * sizeof(float);   // 64 MB
    if (ws_size >= need) {
        // 8 dispatches: [lum+steps1-4], 6x[4 steps] (5-28), [steps29-30+expand].
        float* uA = (float*)d_ws;
        float* uB = uA + NPIX;
        pm_fusedk<0, 4><<<FBLOCKS, FT, 0, stream>>>(
            x, BSTRIDE, uA, PLANE, pdelta, pkappa, Wexp, bexp);
        float* s = uA;
        float* d = uB;
        for (int k = 0; k < 6; ++k) {
            pm_fusedk<1, 4><<<FBLOCKS, FT, 0, stream>>>(
                s, PLANE, d, PLANE, pdelta, pkappa, Wexp, bexp);
            float* t = s; s = d; d = t;
        }
        // u28 is in s. Final 2 steps + expand; d_out written exactly once.
        pm_fusedk<2, 2><<<FBLOCKS, FT, 0, stream>>>(
            s, PLANE, out, BSTRIDE, pdelta, pkappa, Wexp, bexp);
    } else {
        // Fallback: ping-pong in d_out planes 0/1 (swizzled), separate expand.
        float* uA = out;            // plane 0
        float* uB = out + PLANE;    // plane 1
        pm_fusedk<0, 4><<<FBLOCKS, FT, 0, stream>>>(
            x, BSTRIDE, uA, BSTRIDE, pdelta, pkappa, Wexp, bexp);
        float* s = uA;
        float* d = uB;
        for (int k = 0; k < 6; ++k) {
            pm_fusedk<1, 4><<<FBLOCKS, FT, 0, stream>>>(
                s, BSTRIDE, d, BSTRIDE, pdelta, pkappa, Wexp, bexp);
            float* t = s; s = d; d = t;
        }
        // u28 in s; 2 more steps into d, then expand from d (swizzled).
        pm_fusedk<1, 2><<<FBLOCKS, FT, 0, stream>>>(
            s, BSTRIDE, d, BSTRIDE, pdelta, pkappa, Wexp, bexp);
        const int block = 256;
        const int grid_q = (NQUAD + block - 1) / block;
        expand_from<<<grid_q, block, 0, stream>>>(d, BSTRIDE, out, Wexp, bexp);
    }
}